// Round 2
// baseline (434.944 us; speedup 1.0000x reference)
//
#include <hip/hip_runtime.h>

#define KW 11
#define PAD 5
#define TW 32
#define TH 32
#define IW (TW + KW - 1)   // 42
#define IH (TH + KW - 1)   // 42
#define SP 45              // s12 pitch in float2 units (odd-ish: <=2-way banks)
#define HP 35              // hmu/hsq pitch in float2 units
#define H12P 37            // h12 pitch in floats
#define IMH 512
#define IMW 512

typedef float f2 __attribute__((ext_vector_type(2)));

__global__ __launch_bounds__(256, 3) void ssim_main(
    const float* __restrict__ img1, const float* __restrict__ img2,
    const float* __restrict__ window, double* __restrict__ acc,
    unsigned* __restrict__ counter, float* __restrict__ out,
    unsigned nblocks, double inv_n)
{
    __shared__ f2 s12[IH * SP];          // (img1, img2) interleaved
    __shared__ f2 hmu[IH * HP];          // (h-conv of x1, x2)
    __shared__ f2 hsq[IH * HP];          // (h-conv of x1^2, x2^2)
    __shared__ float h12[IH * H12P];     // h-conv of x1*x2
    __shared__ float g[KW];
    __shared__ float wsum[4];

    const int t = threadIdx.x;

    // Recover separable 1D Gaussian: row-sums of the 2D window (cols sum to 1).
    if (t < KW) {
        float s = 0.f;
        for (int j = 0; j < KW; ++j) s += window[(t * KW + j) * 3];
        g[t] = s;
    }

    const int plane = blockIdx.z;
    const size_t base = (size_t)plane * IMH * IMW;
    const int ox0 = blockIdx.x * TW;
    const int oy0 = blockIdx.y * TH;
    const int ix0 = ox0 - PAD;
    const int iy0 = oy0 - PAD;

    // ---- Phase 0: stage (img1, img2) interleaved into LDS with zero-pad.
    for (int idx = t; idx < IH * IW; idx += 256) {
        int r = idx / IW, c = idx - r * IW;
        int gr = iy0 + r, gc = ix0 + c;
        f2 v = {0.f, 0.f};
        if (gr >= 0 && gr < IMH && gc >= 0 && gc < IMW) {
            size_t o = base + (size_t)gr * IMW + gc;
            v.x = img1[o];
            v.y = img2[o];
        }
        s12[r * SP + c] = v;
    }
    __syncthreads();

    // ---- Phase 1: horizontal 11-tap pass, 4 output cols per task.
    // tasks: 42 rows x 8 quads = 336
    for (int task = t; task < IH * 8; task += 256) {
        int row = task >> 3, q = task & 7;
        const f2* src = &s12[row * SP + q * 4];
        f2 v[14];
#pragma unroll
        for (int j = 0; j < 14; ++j) v[j] = src[j];
        f2 p[14]; float x12[14];
#pragma unroll
        for (int j = 0; j < 14; ++j) {
            p[j] = v[j] * v[j];
            x12[j] = v[j].x * v[j].y;
        }
#pragma unroll
        for (int cc = 0; cc < 4; ++cc) {
            f2 mu = {0.f, 0.f}, sq = {0.f, 0.f};
            float m12 = 0.f;
#pragma unroll
            for (int j = 0; j < KW; ++j) {
                float w = g[j];
                f2 w2 = {w, w};
                mu += w2 * v[cc + j];
                sq += w2 * p[cc + j];
                m12 += w * x12[cc + j];
            }
            int o = row * HP + q * 4 + cc;
            hmu[o] = mu;
            hsq[o] = sq;
            h12[row * H12P + q * 4 + cc] = m12;
        }
    }
    __syncthreads();

    // ---- Phase 2: vertical 11-tap pass, 4 output rows per thread + SSIM.
    const float C1v = 0.0001f;
    const float C2v = 0.0009f;
    const int col = t & 31;
    const int rg = t >> 5;       // 8 row groups, rows rg*4 .. rg*4+3
    f2 amu[4] = {{0,0},{0,0},{0,0},{0,0}};
    f2 asq[4] = {{0,0},{0,0},{0,0},{0,0}};
    float a12[4] = {0.f, 0.f, 0.f, 0.f};
#pragma unroll
    for (int i = 0; i < 14; ++i) {
        int row = rg * 4 + i;
        f2 m = hmu[row * HP + col];
        f2 s = hsq[row * HP + col];
        float x = h12[row * H12P + col];
#pragma unroll
        for (int k = 0; k < 4; ++k) {
            int j = i - k;
            if (j >= 0 && j < KW) {
                float w = g[j];
                f2 w2 = {w, w};
                amu[k] += w2 * m;
                asq[k] += w2 * s;
                a12[k] += w * x;
            }
        }
    }
    float lsum = 0.f;
#pragma unroll
    for (int k = 0; k < 4; ++k) {
        float mu1 = amu[k].x, mu2 = amu[k].y;
        float mu1sq = mu1 * mu1, mu2sq = mu2 * mu2, mu12 = mu1 * mu2;
        float sig1 = asq[k].x - mu1sq;
        float sig2 = asq[k].y - mu2sq;
        float sig12 = a12[k] - mu12;
        float num = (2.f * mu12 + C1v) * (2.f * sig12 + C2v);
        float den = (mu1sq + mu2sq + C1v) * (sig1 + sig2 + C2v);
        float r = __builtin_amdgcn_rcpf(den);
        r = r * (2.f - den * r);     // one Newton step: ~full fp32 precision
        lsum += num * r;
    }

    // ---- Reduction: wave shuffle -> cross-wave LDS -> global atomic.
#pragma unroll
    for (int off = 32; off > 0; off >>= 1) lsum += __shfl_down(lsum, off, 64);
    if ((t & 63) == 0) wsum[t >> 6] = lsum;
    __syncthreads();
    if (t == 0) {
        float b = wsum[0] + wsum[1] + wsum[2] + wsum[3];
        atomicAdd(acc, (double)b);
        __threadfence();
        unsigned old = atomicAdd(counter, 1u);
        if (old == nblocks - 1) {
            double s = atomicAdd(acc, 0.0);   // coherent read of final sum
            out[0] = (float)(s * inv_n);
        }
    }
}

extern "C" void kernel_launch(void* const* d_in, const int* in_sizes, int n_in,
                              void* d_out, int out_size, void* d_ws, size_t ws_size,
                              hipStream_t stream) {
    const float* img1   = (const float*)d_in[0];
    const float* img2   = (const float*)d_in[1];
    const float* window = (const float*)d_in[2];
    float* out = (float*)d_out;
    double* acc = (double*)d_ws;
    unsigned* counter = (unsigned*)((char*)d_ws + 8);

    const int nplanes = in_sizes[0] / (IMH * IMW);   // 48
    const long long total = (long long)in_sizes[0];
    const unsigned nblocks = (IMW / TW) * (IMH / TH) * nplanes;

    hipMemsetAsync(d_ws, 0, 16, stream);
    dim3 grid(IMW / TW, IMH / TH, nplanes);
    ssim_main<<<grid, 256, 0, stream>>>(img1, img2, window, acc, counter, out,
                                        nblocks, 1.0 / (double)total);
}